// Round 10
// baseline (315.604 us; speedup 1.0000x reference)
//
#include <hip/hip_runtime.h>
#include <hip/hip_bf16.h>
#include <stdint.h>

#define RCNN_THRES 0.25f
#define YOLO_THRES 0.45f
#define NMS_THRES  0.4f

#define M_BOXES 6144
#define NWORDS  96      // 6144 / 64
#define NGROUPS 24      // 96 / 4
#define SORT_N  8192

#define P_ELEMS  750000
#define P_BLOCKS 2930   // ceil(750000/256)
#define R_BLOCKS 1536   // 6144 rows / 4 waves per block
#define B_BLOCKS 24     // 6144 / 256
#define MB_BLOCKS 1536  // mask build: 6144 rows / 4 waves per block

typedef unsigned long long u64;

__device__ inline float wave_sum(float v) {
#pragma unroll
    for (int o = 32; o > 0; o >>= 1) v += __shfl_xor(v, o);
    return v;
}
__device__ inline float wave_max(float v) {
#pragma unroll
    for (int o = 32; o > 0; o >>= 1) v = fmaxf(v, __shfl_xor(v, o));
    return v;
}

// broadcast 64-bit value from lane l (wave-uniform l) via v_readlane pairs
__device__ inline u64 readlane_u64(u64 v, int l) {
    unsigned lo = (unsigned)__builtin_amdgcn_readlane((int)(unsigned)v, l);
    unsigned hi = (unsigned)__builtin_amdgcn_readlane((int)(unsigned)(v >> 32), l);
    return ((u64)hi << 32) | (u64)lo;
}

__device__ inline float box_loss_term(float c5, float c4) {
    // s = 1/(0.5-0.45) = 20
    float a = fminf(fmaxf((c5 - YOLO_THRES) * 20.0f, 0.0f), 1.0f);
    float b = fminf(fmaxf((c4 - YOLO_THRES) * 20.0f, 0.0f), 1.0f);
    return -a * logf(1.0f - c5 + 0.01f) - b * logf(1.0f - c4 + 0.01f);
}

__device__ inline bool iou_gt(float x1a, float y1a, float x2a, float y2a, float aa,
                              float x1b, float y1b, float x2b, float y2b, float ab) {
    float iw = fmaxf(fminf(x2a, x2b) - fmaxf(x1a, x1b), 0.0f);
    float ih = fmaxf(fminf(y2a, y2b) - fmaxf(y1a, y1b), 0.0f);
    float inter = iw * ih;
    float uni = aa + ab - inter;
    return (inter / fmaxf(uni, 1e-12f)) > NMS_THRES;
}

// ---------------------------------------------------------------------------
// Kernel B: stable descending sort by conf (key = conf_bits<<13 | (8191-idx)),
// then gather sorted corner/area/conf/c5 SoA + valid bit-words. (unchanged)
// ---------------------------------------------------------------------------
__global__ __launch_bounds__(1024) void sort_boxes(
    const float* __restrict__ boxes,
    float* __restrict__ sx1, float* __restrict__ sy1,
    float* __restrict__ sx2, float* __restrict__ sy2,
    float* __restrict__ sarea, float* __restrict__ sconf, float* __restrict__ sc5,
    u64* __restrict__ Vw) {
    __shared__ u64 keys[SORT_N];
    const int tid = threadIdx.x;

#pragma unroll
    for (int s = 0; s < SORT_N / 1024; ++s) {
        int p = tid + s * 1024;
        u64 key = 0ull;
        if (p < M_BOXES) {
            unsigned int bits = __float_as_uint(boxes[p * 6 + 4]);
            key = ((u64)bits << 13) | (u64)(8191 - p);
        }
        keys[p] = key;
    }
    for (int k = 2; k <= SORT_N; k <<= 1) {
        for (int j = k >> 1; j > 0; j >>= 1) {
            __syncthreads();
#pragma unroll
            for (int s = 0; s < SORT_N / 2048; ++s) {   // 4096 pairs / 1024 threads
                int q = tid + s * 1024;
                int i = ((q & ~(j - 1)) << 1) | (q & (j - 1));
                int p2 = i | j;
                u64 a = keys[i], b = keys[p2];
                bool up = ((i & k) == 0);
                if ((a < b) == up) { keys[i] = b; keys[p2] = a; }  // descending overall
            }
        }
    }
    __syncthreads();
#pragma unroll
    for (int s = 0; s < SORT_N / 1024; ++s) {
        int p = tid + s * 1024;
        bool validp = false;
        if (p < M_BOXES) {
            int idx = 8191 - (int)(keys[p] & 0x1FFFull);
            const float* b6 = boxes + idx * 6;
            float x = b6[0], y = b6[1], wd = b6[2], ht = b6[3];
            float conf = b6[4], c5 = b6[5];
            sx1[p] = x - wd * 0.5f;
            sx2[p] = x + wd * 0.5f;
            sy1[p] = y - ht * 0.5f;
            sy2[p] = y + ht * 0.5f;
            sarea[p] = wd * ht;
            sconf[p] = conf;
            sc5[p] = c5;
            validp = conf > YOLO_THRES;
        }
        u64 bits = __ballot(validp);
        int word = (tid >> 6) + s * 16;
        if ((tid & 63) == 0 && word < NWORDS) Vw[word] = bits;
    }
}

// ---------------------------------------------------------------------------
// Mega kernel: role-split by blockIdx (unchanged).
// ---------------------------------------------------------------------------
__global__ __launch_bounds__(256) void mega_kernel(
    const float* __restrict__ img, const float* __restrict__ p0,
    const float* __restrict__ p1, const float* __restrict__ p2,
    const float* __restrict__ probs, const float* __restrict__ boxes,
    const float* __restrict__ sx1, const float* __restrict__ sy1,
    const float* __restrict__ sx2, const float* __restrict__ sy2,
    const float* __restrict__ sarea, const u64* __restrict__ Vw,
    u64* __restrict__ mask, float* __restrict__ acc) {
    __shared__ float fred[8];
    const int tid = threadIdx.x, lane = tid & 63, wid = tid >> 6;
    const int bid = blockIdx.x;

    if (bid < MB_BLOCKS) {
        int row = bid * 4 + wid;
        if (!((Vw[row >> 6] >> (row & 63)) & 1ull)) return;  // invalid: never kept
        float rx1 = sx1[row], ry1 = sy1[row], rx2 = sx2[row], ry2 = sy2[row];
        float ra = sarea[row];
        u64* mrow = mask + (size_t)row * NWORDS;
        for (int w = row >> 6; w < NWORDS; ++w) {
            if (Vw[w] == 0ull) break;   // prefix property: rest are all-invalid
            int j = w * 64 + lane;
            bool pred = (j > row) &&
                        iou_gt(rx1, ry1, rx2, ry2, ra,
                               sx1[j], sy1[j], sx2[j], sy2[j], sarea[j]);
            u64 bits = __ballot(pred);
            if (lane == 0) mrow[w] = bits;
        }
        return;
    } else if (bid < MB_BLOCKS + P_BLOCKS) {
        int e = (bid - MB_BLOCKS) * 256 + tid;
        float local = 0.0f;
        if (e < P_ELEMS) {
            float v = img[e];
            int c = e / 250000;
            int rem = e - c * 250000;
            int y = rem / 500;
            int x = rem - y * 500;
            if (x >= 50 && x < 450) {
                int px = x - 50;
                if (y >= 75 && y < 125)       v += p0[c * 20000 + (y - 75) * 400 + px];
                else if (y >= 225 && y < 275) v += p1[c * 20000 + (y - 225) * 400 + px];
                else if (y >= 375 && y < 425) v += p2[c * 20000 + (y - 375) * 400 + px];
            }
            local = fmaxf(-v, 0.0f) + fmaxf(v - 1.0f, 0.0f);
        }
        local = wave_sum(local);
        if (lane == 0) fred[wid] = local;
        __syncthreads();
        if (tid == 0) atomicAdd(&acc[0], fred[0] + fred[1] + fred[2] + fred[3]);
    } else if (bid < MB_BLOCKS + P_BLOCKS + R_BLOCKS) {
        int row = (bid - MB_BLOCKS - P_BLOCKS) * 4 + wid;
        const float* pr = probs + row * 81;
        float m = pr[lane];                          // cols 0..63
        if (lane < 16) m = fmaxf(m, pr[64 + lane]);  // cols 64..79 (col 80 excluded)
        m = wave_max(m);
        float t = 0.0f;
        if (lane == 0 && m > RCNN_THRES) {
            float bp = pr[80];
            float cl = fminf(fmaxf((m - RCNN_THRES) * (1.0f / (0.3f - RCNN_THRES)), 0.0f), 1.0f);
            t = -logf(bp + 0.001f) - cl * logf(1.0f - m + 0.001f);
        }
        if (lane == 0) fred[wid] = t;
        __syncthreads();
        if (tid == 0) atomicAdd(&acc[1], fred[0] + fred[1] + fred[2] + fred[3]);
    } else {
        int i = (bid - MB_BLOCKS - P_BLOCKS - R_BLOCKS) * 256 + tid;
        float l = 0.0f, cnt = 0.0f;
        if (i < M_BOXES) {
            float conf = boxes[i * 6 + 4];
            if (conf > YOLO_THRES) {
                float c5 = boxes[i * 6 + 5];
                l = box_loss_term(c5, conf);
                cnt = 1.0f;
            }
        }
        l = wave_sum(l);
        cnt = wave_sum(cnt);
        if (lane == 0) { fred[wid] = l; fred[4 + wid] = cnt; }
        __syncthreads();
        if (tid == 0) {
            atomicAdd(&acc[2], fred[0] + fred[1] + fred[2] + fred[3]);
            atomicAdd(&acc[3], fred[4] + fred[5] + fred[6] + fred[7]);
        }
    }
}

// ---------------------------------------------------------------------------
// Walk kernel: one wave, GROUP-OF-4 words per serial step.
// Per group g (words W..W+3, W=4g):
//  - slice regs (prefetched one group ahead): lane l holds, for each word c,
//    row (W+c)*64+l's 4 mask words [W..W+3] as 2 ulonglong2 (Ac=cols W,W+1;
//    Bc=cols W+2,W+3). Independent of suppression -> fully hideable.
//  - 4 register-only walks: diag + intra-group forward suppression via
//    readlane into group-sup words gs1..gs3. No memory in the chain.
//  - ONE batched cross-group load round (R8-proven batch-of-16 ulonglong2,
//    lane l owns words 2l/2l+1), OR'd into distributed sup.
// Serial HBM waits: 53 words -> ~14 groups.
// ---------------------------------------------------------------------------
__global__ __launch_bounds__(64) void nms_walk(
    const float* __restrict__ acc, const u64* __restrict__ Vw,
    const u64* __restrict__ mask,
    const float* __restrict__ sconf, const float* __restrict__ sc5,
    float* __restrict__ out) {
    const int lane = threadIdx.x;
    const bool haslane = lane < NWORDS / 2;   // lane owns words 2l, 2l+1
    u64 vwx = haslane ? Vw[2 * lane] : 0ull;
    u64 vwy = haslane ? Vw[2 * lane + 1] : 0ull;
    u64 supx = 0ull, supy = 0ull;
    u64 kwx = 0ull, kwy = 0ull;

    // slice registers for group 0
    ulonglong2 A0, B0, A1, B1, A2, B2, A3, B3;
    {
        const ulonglong2* p0 = (const ulonglong2*)(mask + (size_t)(0 * 64 + lane) * NWORDS + 0);
        const ulonglong2* p1 = (const ulonglong2*)(mask + (size_t)(1 * 64 + lane) * NWORDS + 0);
        const ulonglong2* p2 = (const ulonglong2*)(mask + (size_t)(2 * 64 + lane) * NWORDS + 0);
        const ulonglong2* p3 = (const ulonglong2*)(mask + (size_t)(3 * 64 + lane) * NWORDS + 0);
        A0 = p0[0]; B0 = p0[1];
        A1 = p1[0]; B1 = p1[1];
        A2 = p2[0]; B2 = p2[1];
        A3 = p3[0]; B3 = p3[1];
    }

    for (int g = 0; g < NGROUPS; ++g) {
        const int W = 4 * g;
        const int h0 = 2 * g, h1 = 2 * g + 1;

        // prefetch next group's slices (independent; consumed next iteration)
        ulonglong2 A0n{}, B0n{}, A1n{}, B1n{}, A2n{}, B2n{}, A3n{}, B3n{};
        if (g + 1 < NGROUPS) {
            const int Wn = W + 4;
            const ulonglong2* q0 = (const ulonglong2*)(mask + (size_t)((Wn + 0) * 64 + lane) * NWORDS + Wn);
            const ulonglong2* q1 = (const ulonglong2*)(mask + (size_t)((Wn + 1) * 64 + lane) * NWORDS + Wn);
            const ulonglong2* q2 = (const ulonglong2*)(mask + (size_t)((Wn + 2) * 64 + lane) * NWORDS + Wn);
            const ulonglong2* q3 = (const ulonglong2*)(mask + (size_t)((Wn + 3) * 64 + lane) * NWORDS + Wn);
            A0n = q0[0]; B0n = q0[1];
            A1n = q1[0]; B1n = q1[1];
            A2n = q2[0]; B2n = q2[1];
            A3n = q3[0]; B3n = q3[1];
        }

        u64 gs1 = 0ull, gs2 = 0ull, gs3 = 0ull;   // group-local sup for W+1..W+3
        u64 curw0 = 0ull, curw1 = 0ull, curw2 = 0ull, curw3 = 0ull;

        // ---- word W (even, lane h0, slot x) ----
        u64 vw = readlane_u64(vwx, h0);
        if (vw == 0ull) break;                    // prefix property: all done
        {
            u64 supw = readlane_u64(supx, h0);
            u64 cur = vw & ~supw, rem = cur;
            while (rem) {
                int t = __builtin_amdgcn_readfirstlane((int)__builtin_ctzll(rem));
                u64 d = readlane_u64(A0.x, t);
                gs1 |= readlane_u64(A0.y, t);
                gs2 |= readlane_u64(B0.x, t);
                gs3 |= readlane_u64(B0.y, t);
                cur &= ~d; rem &= ~d; rem &= rem - 1;
            }
            curw0 = cur;
            if (lane == h0) kwx = cur;
        }
        // ---- word W+1 (odd, lane h0, slot y) ----
        vw = readlane_u64(vwy, h0);
        if (vw != 0ull) {
            u64 supw = readlane_u64(supy, h0) | gs1;
            u64 cur = vw & ~supw, rem = cur;
            while (rem) {
                int t = __builtin_amdgcn_readfirstlane((int)__builtin_ctzll(rem));
                u64 d = readlane_u64(A1.y, t);
                gs2 |= readlane_u64(B1.x, t);
                gs3 |= readlane_u64(B1.y, t);
                cur &= ~d; rem &= ~d; rem &= rem - 1;
            }
            curw1 = cur;
            if (lane == h0) kwy = cur;
        }
        // ---- word W+2 (even, lane h1, slot x) ----
        vw = readlane_u64(vwx, h1);
        if (vw != 0ull) {
            u64 supw = readlane_u64(supx, h1) | gs2;
            u64 cur = vw & ~supw, rem = cur;
            while (rem) {
                int t = __builtin_amdgcn_readfirstlane((int)__builtin_ctzll(rem));
                u64 d = readlane_u64(B2.x, t);
                gs3 |= readlane_u64(B2.y, t);
                cur &= ~d; rem &= ~d; rem &= rem - 1;
            }
            curw2 = cur;
            if (lane == h1) kwx = cur;
        }
        // ---- word W+3 (odd, lane h1, slot y) ----
        vw = readlane_u64(vwy, h1);
        if (vw != 0ull) {
            u64 supw = readlane_u64(supy, h1) | gs3;
            u64 cur = vw & ~supw, rem = cur;
            while (rem) {
                int t = __builtin_amdgcn_readfirstlane((int)__builtin_ctzll(rem));
                u64 d = readlane_u64(B3.y, t);
                cur &= ~d; rem &= ~d; rem &= rem - 1;
            }
            curw3 = cur;
            if (lane == h1) kwy = cur;
        }

        // ---- cross-group suppression: batches of 16 kept rows ----
        const int Wend = W + 3;
        const bool ldp = haslane && (2 * lane + 1 > Wend);
        const bool ldx = haslane && (2 * lane > Wend);
        u64 kk0 = curw0, kk1 = curw1, kk2 = curw2, kk3 = curw3;
        while (kk0 | kk1 | kk2 | kk3) {
            int rows[16];
#pragma unroll
            for (int s = 0; s < 16; ++s) {
                int r;
                if (kk0)      { r = ((W    ) << 6) + (int)__builtin_ctzll(kk0); kk0 &= kk0 - 1; }
                else if (kk1) { r = ((W + 1) << 6) + (int)__builtin_ctzll(kk1); kk1 &= kk1 - 1; }
                else if (kk2) { r = ((W + 2) << 6) + (int)__builtin_ctzll(kk2); kk2 &= kk2 - 1; }
                else if (kk3) { r = ((W + 3) << 6) + (int)__builtin_ctzll(kk3); kk3 &= kk3 - 1; }
                else          { r = rows[0]; }   // pad: OR is idempotent
                rows[s] = r;
            }
            if (ldp) {
                ulonglong2 m[16];
#pragma unroll
                for (int s = 0; s < 16; ++s)
                    m[s] = *(const ulonglong2*)(mask + (size_t)rows[s] * NWORDS + 2 * lane);
                u64 ox = 0ull, oy = 0ull;
#pragma unroll
                for (int s = 0; s < 16; ++s) { ox |= m[s].x; oy |= m[s].y; }
                supy |= oy;
                if (ldx) supx |= ox;
            }
        }

        A0 = A0n; B0 = B0n; A1 = A1n; B1 = B1n;
        A2 = A2n; B2 = B2n; A3 = A3n; B3 = B3n;
    }

    // b_nms_loss / b_nms_cnt: lane processes its own words' kept bits
    float nl = 0.0f, nc = 0.0f;
    u64 k = kwx;
    while (k) {
        int j = __builtin_ctzll(k);
        k &= k - 1;
        int p = (lane << 7) + j;              // word 2*lane
        nl += box_loss_term(sc5[p], sconf[p]);
        nc += 1.0f;
    }
    k = kwy;
    while (k) {
        int j = __builtin_ctzll(k);
        k &= k - 1;
        int p = (lane << 7) + 64 + j;         // word 2*lane+1
        nl += box_loss_term(sc5[p], sconf[p]);
        nc += 1.0f;
    }
    nl = wave_sum(nl);
    nc = wave_sum(nc);
    if (lane == 0) {
        float p_loss = acc[0], r_loss = acc[1], b_loss = acc[2], b_cnt = acc[3];
        float yolo = b_loss + nl * (b_cnt / fmaxf(nc, 1.0f));
        out[0] = r_loss * 0.8f + yolo + p_loss;
    }
}

// ---------------------------------------------------------------------------
extern "C" void kernel_launch(void* const* d_in, const int* in_sizes, int n_in,
                              void* d_out, int out_size, void* d_ws, size_t ws_size,
                              hipStream_t stream) {
    const float* img   = (const float*)d_in[0];
    const float* p0    = (const float*)d_in[1];
    const float* p1    = (const float*)d_in[2];
    const float* p2    = (const float*)d_in[3];
    const float* probs = (const float*)d_in[4];
    const float* boxes = (const float*)d_in[5];
    float* out = (float*)d_out;

    char* ws = (char*)d_ws;
    float* acc = (float*)ws;                // 8 floats @ 0 (acc[0..3] used)
    u64* Vw = (u64*)(ws + 64);              // 96 words
    float* sx1 = (float*)(ws + 1024);
    float* sy1 = sx1 + M_BOXES;
    float* sx2 = sy1 + M_BOXES;
    float* sy2 = sx2 + M_BOXES;
    float* sarea = sy2 + M_BOXES;
    float* sconf = sarea + M_BOXES;
    float* sc5 = sconf + M_BOXES;
    // mask: 6144 rows x 96 words x 8 B = 4.72 MB @ offset 173056 (16-aligned)
    u64* mask = (u64*)(ws + 173056);

    hipMemsetAsync(acc, 0, 32, stream);
    sort_boxes<<<1, 1024, 0, stream>>>(boxes, sx1, sy1, sx2, sy2, sarea, sconf, sc5, Vw);
    mega_kernel<<<MB_BLOCKS + P_BLOCKS + R_BLOCKS + B_BLOCKS, 256, 0, stream>>>(
        img, p0, p1, p2, probs, boxes, sx1, sy1, sx2, sy2, sarea, Vw, mask, acc);
    nms_walk<<<1, 64, 0, stream>>>(acc, Vw, mask, sconf, sc5, out);
}

// Round 11
// 222.537 us; speedup vs baseline: 1.4182x; 1.4182x over previous
//
#include <hip/hip_runtime.h>
#include <hip/hip_bf16.h>
#include <stdint.h>

#define RCNN_THRES 0.25f
#define YOLO_THRES 0.45f
#define NMS_THRES  0.4f

#define M_BOXES 6144
#define NWORDS  96      // 6144 / 64
#define NGROUPS 24      // 96 / 4
#define SORT_N  4096    // valid-only sort capacity

#define P_ELEMS  750000
#define P_BLOCKS 2930   // ceil(750000/256)
#define R_BLOCKS 1536   // 6144 rows / 4 waves per block
#define B_BLOCKS 24     // 6144 / 256
#define MB_BLOCKS 1536  // mask build: 6144 rows / 4 waves per block

typedef unsigned long long u64;

__device__ inline float wave_sum(float v) {
#pragma unroll
    for (int o = 32; o > 0; o >>= 1) v += __shfl_xor(v, o);
    return v;
}
__device__ inline float wave_max(float v) {
#pragma unroll
    for (int o = 32; o > 0; o >>= 1) v = fmaxf(v, __shfl_xor(v, o));
    return v;
}

// broadcast 64-bit value from lane l (wave-uniform l) via v_readlane pairs
__device__ inline u64 readlane_u64(u64 v, int l) {
    unsigned lo = (unsigned)__builtin_amdgcn_readlane((int)(unsigned)v, l);
    unsigned hi = (unsigned)__builtin_amdgcn_readlane((int)(unsigned)(v >> 32), l);
    return ((u64)hi << 32) | (u64)lo;
}

__device__ inline float box_loss_term(float c5, float c4) {
    float a = fminf(fmaxf((c5 - YOLO_THRES) * 20.0f, 0.0f), 1.0f);
    float b = fminf(fmaxf((c4 - YOLO_THRES) * 20.0f, 0.0f), 1.0f);
    return -a * logf(1.0f - c5 + 0.01f) - b * logf(1.0f - c4 + 0.01f);
}

__device__ inline bool iou_gt(float x1a, float y1a, float x2a, float y2a, float aa,
                              float x1b, float y1b, float x2b, float y2b, float ab) {
    float iw = fmaxf(fminf(x2a, x2b) - fmaxf(x1a, x1b), 0.0f);
    float ih = fmaxf(fminf(y2a, y2b) - fmaxf(y1a, y1b), 0.0f);
    float inter = iw * ih;
    float uni = aa + ab - inter;
    return (inter / fmaxf(uni, 1e-12f)) > NMS_THRES;
}

// valid-word for sorted position space given nvalid (validity = prefix)
__device__ inline u64 vw_word(int w, int nv) {
    int rem = nv - (w << 6);
    if (rem >= 64) return ~0ull;
    if (rem <= 0) return 0ull;
    return (1ull << rem) - 1ull;
}

// ---------------------------------------------------------------------------
// Sort kernel: ballot-compact VALID boxes (stable, key keeps original index),
// bitonic-sort 4096 keys descending, emit sorted SoA + nvalid.
// Invalid boxes are never needed downstream (mask rows/cols, walk, b_nms all
// restricted to the valid prefix; b_loss reads original boxes in mega).
// ---------------------------------------------------------------------------
__global__ __launch_bounds__(1024) void sort_boxes(
    const float* __restrict__ boxes,
    float* __restrict__ sx1, float* __restrict__ sy1,
    float* __restrict__ sx2, float* __restrict__ sy2,
    float* __restrict__ sarea, float* __restrict__ sconf, float* __restrict__ sc5,
    int* __restrict__ nvp) {
    __shared__ u64 keys[SORT_N];
    __shared__ u64 bwords[96];
    __shared__ int wcnt[97];
    const int tid = threadIdx.x;
    const int lane = tid & 63;

    // Pass A: validity ballots per 64-chunk + zero-init keys
#pragma unroll
    for (int s = 0; s < 6; ++s) {
        int p = tid + s * 1024;
        bool valid = boxes[p * 6 + 4] > YOLO_THRES;
        u64 b = __ballot(valid);
        int chunk = s * 16 + (tid >> 6);
        if (lane == 0) { bwords[chunk] = b; wcnt[chunk] = __popcll(b); }
    }
#pragma unroll
    for (int s = 0; s < 4; ++s) keys[tid + s * 1024] = 0ull;
    __syncthreads();
    if (tid == 0) {                      // serial 96-scan: trivial
        int run = 0;
        for (int i = 0; i < 96; ++i) { int t = wcnt[i]; wcnt[i] = run; run += t; }
        wcnt[96] = run;
        *nvp = run;
    }
    __syncthreads();
    // Pass B: stable compaction of valid keys
#pragma unroll
    for (int s = 0; s < 6; ++s) {
        int p = tid + s * 1024;
        if (boxes[p * 6 + 4] > YOLO_THRES) {
            int chunk = s * 16 + (tid >> 6);
            u64 b = bwords[chunk];
            int pos = wcnt[chunk] + __popcll(b & ((1ull << lane) - 1ull));
            if (pos < SORT_N) {
                unsigned int bits = __float_as_uint(boxes[p * 6 + 4]);
                keys[pos] = ((u64)bits << 13) | (u64)(8191 - p);
            }
        }
    }
    // bitonic sort 4096 descending
    for (int k = 2; k <= SORT_N; k <<= 1) {
        for (int j = k >> 1; j > 0; j >>= 1) {
            __syncthreads();
#pragma unroll
            for (int s = 0; s < SORT_N / 2048; ++s) {   // 2048 pairs / 1024 threads
                int q = tid + s * 1024;
                int i = ((q & ~(j - 1)) << 1) | (q & (j - 1));
                int p2 = i | j;
                u64 a = keys[i], b = keys[p2];
                bool up = ((i & k) == 0);
                if ((a < b) == up) { keys[i] = b; keys[p2] = a; }
            }
        }
    }
    __syncthreads();
    const int nv = wcnt[96];
#pragma unroll
    for (int s = 0; s < 4; ++s) {
        int p = tid + s * 1024;
        if (p < nv) {
            int idx = 8191 - (int)(keys[p] & 0x1FFFull);
            const float* b6 = boxes + idx * 6;
            float x = b6[0], y = b6[1], wd = b6[2], ht = b6[3];
            sx1[p] = x - wd * 0.5f;
            sx2[p] = x + wd * 0.5f;
            sy1[p] = y - ht * 0.5f;
            sy2[p] = y + ht * 0.5f;
            sarea[p] = wd * ht;
            sconf[p] = b6[4];
            sc5[p] = b6[5];
        }
    }
}

// ---------------------------------------------------------------------------
// Mega kernel: role-split by blockIdx. Mask rows now = valid prefix [0, nv).
// ---------------------------------------------------------------------------
__global__ __launch_bounds__(256) void mega_kernel(
    const float* __restrict__ img, const float* __restrict__ p0,
    const float* __restrict__ p1, const float* __restrict__ p2,
    const float* __restrict__ probs, const float* __restrict__ boxes,
    const float* __restrict__ sx1, const float* __restrict__ sy1,
    const float* __restrict__ sx2, const float* __restrict__ sy2,
    const float* __restrict__ sarea, const int* __restrict__ nvp,
    u64* __restrict__ mask, float* __restrict__ acc) {
    __shared__ float fred[8];
    const int tid = threadIdx.x, lane = tid & 63, wid = tid >> 6;
    const int bid = blockIdx.x;

    if (bid < MB_BLOCKS) {
        const int nv = *nvp;
        int row = bid * 4 + wid;
        if (row >= nv) return;
        const int nwa = (nv + 63) >> 6;
        float rx1 = sx1[row], ry1 = sy1[row], rx2 = sx2[row], ry2 = sy2[row];
        float ra = sarea[row];
        u64* mrow = mask + (size_t)row * NWORDS;
        for (int w = row >> 6; w < nwa; ++w) {
            int j = w * 64 + lane;
            bool pred = (j > row) &&
                        iou_gt(rx1, ry1, rx2, ry2, ra,
                               sx1[j], sy1[j], sx2[j], sy2[j], sarea[j]);
            u64 bits = __ballot(pred);
            if (lane == 0) mrow[w] = bits;
        }
        return;
    } else if (bid < MB_BLOCKS + P_BLOCKS) {
        int e = (bid - MB_BLOCKS) * 256 + tid;
        float local = 0.0f;
        if (e < P_ELEMS) {
            float v = img[e];
            int c = e / 250000;
            int rem = e - c * 250000;
            int y = rem / 500;
            int x = rem - y * 500;
            if (x >= 50 && x < 450) {
                int px = x - 50;
                if (y >= 75 && y < 125)       v += p0[c * 20000 + (y - 75) * 400 + px];
                else if (y >= 225 && y < 275) v += p1[c * 20000 + (y - 225) * 400 + px];
                else if (y >= 375 && y < 425) v += p2[c * 20000 + (y - 375) * 400 + px];
            }
            local = fmaxf(-v, 0.0f) + fmaxf(v - 1.0f, 0.0f);
        }
        local = wave_sum(local);
        if (lane == 0) fred[wid] = local;
        __syncthreads();
        if (tid == 0) atomicAdd(&acc[0], fred[0] + fred[1] + fred[2] + fred[3]);
    } else if (bid < MB_BLOCKS + P_BLOCKS + R_BLOCKS) {
        int row = (bid - MB_BLOCKS - P_BLOCKS) * 4 + wid;
        const float* pr = probs + row * 81;
        float m = pr[lane];
        if (lane < 16) m = fmaxf(m, pr[64 + lane]);
        m = wave_max(m);
        float t = 0.0f;
        if (lane == 0 && m > RCNN_THRES) {
            float bp = pr[80];
            float cl = fminf(fmaxf((m - RCNN_THRES) * (1.0f / (0.3f - RCNN_THRES)), 0.0f), 1.0f);
            t = -logf(bp + 0.001f) - cl * logf(1.0f - m + 0.001f);
        }
        if (lane == 0) fred[wid] = t;
        __syncthreads();
        if (tid == 0) atomicAdd(&acc[1], fred[0] + fred[1] + fred[2] + fred[3]);
    } else {
        int i = (bid - MB_BLOCKS - P_BLOCKS - R_BLOCKS) * 256 + tid;
        float l = 0.0f, cnt = 0.0f;
        if (i < M_BOXES) {
            float conf = boxes[i * 6 + 4];
            if (conf > YOLO_THRES) {
                float c5 = boxes[i * 6 + 5];
                l = box_loss_term(c5, conf);
                cnt = 1.0f;
            }
        }
        l = wave_sum(l);
        cnt = wave_sum(cnt);
        if (lane == 0) { fred[wid] = l; fred[4 + wid] = cnt; }
        __syncthreads();
        if (tid == 0) {
            atomicAdd(&acc[2], fred[0] + fred[1] + fred[2] + fred[3]);
            atomicAdd(&acc[3], fred[4] + fred[5] + fred[6] + fred[7]);
        }
    }
}

// ---------------------------------------------------------------------------
// Walk kernel: 8 waves, 1 block. Per group of 4 words:
//   all waves : issue stage of group g+1 slices (1x16B load/thread)
//   wave 0    : slices LDS->regs, sup from 8 LDS copies, register walk,
//               write KW[W..W+3]
//   barrier A
//   all waves : write staged slices to LDS; split kept rows round-robin;
//               each wave loads a full mask row coalesced (64 lanes x 16B)
//               and ORs into its own SUPC copy  -> 8-wave MLP on HBM lines
//   barrier B
// ---------------------------------------------------------------------------
__global__ __launch_bounds__(512) void nms_walk(
    const float* __restrict__ acc, const int* __restrict__ nvp,
    const u64* __restrict__ mask,
    const float* __restrict__ sconf, const float* __restrict__ sc5,
    float* __restrict__ out) {
    __shared__ u64 SLICE[2][1024];   // [buf][grouprow*4 + c]: words W..W+3 of row
    __shared__ u64 SUPC[8][NWORDS];  // per-wave suppression copies
    __shared__ u64 KW[NWORDS];       // kept words
    __shared__ float fred[16];

    const int tid = threadIdx.x, lane = tid & 63, wid = tid >> 6;
    const int nv = *nvp;
    const int nwa = (nv + 63) >> 6;
    const int ngrp = (nwa + 3) >> 2;

    // init + stage group 0
    for (int i = tid; i < 8 * NWORDS; i += 512) ((u64*)SUPC)[i] = 0ull;
    for (int i = tid; i < NWORDS; i += 512) KW[i] = 0ull;
    {
        int r = tid >> 1, h = tid & 1;
        ulonglong2 m = *(const ulonglong2*)(mask + (size_t)r * NWORDS + 2 * h);
        *(ulonglong2*)&SLICE[0][r * 4 + 2 * h] = m;
    }
    __syncthreads();

    for (int g = 0; g < ngrp; ++g) {
        const int W = 4 * g;
        const int buf = g & 1;

        // issue stage of next group's slices (held in regs until after barrier A)
        ulonglong2 stg{};
        const bool do_stage = (g + 1 < ngrp);
        if (do_stage) {
            int r = tid >> 1, h = tid & 1;
            stg = *(const ulonglong2*)(mask +
                    (size_t)((g + 1) * 256 + r) * NWORDS + (4 * (g + 1) + 2 * h));
        }

        if (wid == 0) {
            // slices -> registers (lane l holds rows c*64+l for c=0..3)
            const u64* SL = SLICE[buf];
            ulonglong2 S0lo = *(const ulonglong2*)&SL[(0 * 64 + lane) * 4];
            ulonglong2 S0hi = *(const ulonglong2*)&SL[(0 * 64 + lane) * 4 + 2];
            ulonglong2 S1lo = *(const ulonglong2*)&SL[(1 * 64 + lane) * 4];
            ulonglong2 S1hi = *(const ulonglong2*)&SL[(1 * 64 + lane) * 4 + 2];
            ulonglong2 S2lo = *(const ulonglong2*)&SL[(2 * 64 + lane) * 4];
            ulonglong2 S2hi = *(const ulonglong2*)&SL[(2 * 64 + lane) * 4 + 2];
            ulonglong2 S3lo = *(const ulonglong2*)&SL[(3 * 64 + lane) * 4];
            ulonglong2 S3hi = *(const ulonglong2*)&SL[(3 * 64 + lane) * 4 + 2];
            (void)S1lo; (void)S2lo; (void)S3lo;

            // combined suppression for this group's words (uniform LDS reads)
            u64 supW0 = 0ull, supW1 = 0ull, supW2 = 0ull, supW3 = 0ull;
#pragma unroll
            for (int k = 0; k < 8; ++k) {
                ulonglong2 a = *(const ulonglong2*)&SUPC[k][W];
                ulonglong2 b = *(const ulonglong2*)&SUPC[k][W + 2];
                supW0 |= a.x; supW1 |= a.y; supW2 |= b.x; supW3 |= b.y;
            }

            u64 gs1 = 0ull, gs2 = 0ull, gs3 = 0ull;
            u64 vw, cur, rem;
            // word W+0
            vw = vw_word(W + 0, nv);
            if (vw) {
                cur = vw & ~supW0; rem = cur;
                while (rem) {
                    int t = __builtin_amdgcn_readfirstlane((int)__builtin_ctzll(rem));
                    u64 d = readlane_u64(S0lo.x, t);
                    gs1 |= readlane_u64(S0lo.y, t);
                    gs2 |= readlane_u64(S0hi.x, t);
                    gs3 |= readlane_u64(S0hi.y, t);
                    cur &= ~d; rem &= ~d; rem &= rem - 1;
                }
                if (lane == 0) KW[W + 0] = cur;
            }
            // word W+1
            vw = vw_word(W + 1, nv);
            if (vw) {
                cur = vw & ~(supW1 | gs1); rem = cur;
                while (rem) {
                    int t = __builtin_amdgcn_readfirstlane((int)__builtin_ctzll(rem));
                    u64 d = readlane_u64(S1lo.y, t);
                    gs2 |= readlane_u64(S1hi.x, t);
                    gs3 |= readlane_u64(S1hi.y, t);
                    cur &= ~d; rem &= ~d; rem &= rem - 1;
                }
                if (lane == 0) KW[W + 1] = cur;
            }
            // word W+2
            vw = vw_word(W + 2, nv);
            if (vw) {
                cur = vw & ~(supW2 | gs2); rem = cur;
                while (rem) {
                    int t = __builtin_amdgcn_readfirstlane((int)__builtin_ctzll(rem));
                    u64 d = readlane_u64(S2hi.x, t);
                    gs3 |= readlane_u64(S2hi.y, t);
                    cur &= ~d; rem &= ~d; rem &= rem - 1;
                }
                if (lane == 0) KW[W + 2] = cur;
            }
            // word W+3
            vw = vw_word(W + 3, nv);
            if (vw) {
                cur = vw & ~(supW3 | gs3); rem = cur;
                while (rem) {
                    int t = __builtin_amdgcn_readfirstlane((int)__builtin_ctzll(rem));
                    u64 d = readlane_u64(S3hi.y, t);
                    cur &= ~d; rem &= ~d; rem &= rem - 1;
                }
                if (lane == 0) KW[W + 3] = cur;
            }
        }
        __syncthreads();   // A: KW ready; wave0 done with SLICE[buf]

        // write staged slices for group g+1
        if (do_stage) {
            int r = tid >> 1, h = tid & 1;
            *(ulonglong2*)&SLICE[buf ^ 1][r * 4 + 2 * h] = stg;
        }

        // cross-group suppression: distribute kept rows over 8 waves,
        // one coalesced full-row load per kept row
        const int Wp4 = W + 4;
        const int nwrem = NWORDS - Wp4;
        if (nwrem > 0) {
            u64 kw0 = KW[W], kw1 = KW[W + 1], kw2 = KW[W + 2], kw3 = KW[W + 3];
            int idx = 0, nmine = 0;
            int b0 = 0, b1 = 0, b2 = 0, b3 = 0;
            const bool lactive = (2 * lane) < nwrem;
            const u64* bp = mask + Wp4 + 2 * lane;
            u64* scrow = &SUPC[wid][0];
#pragma unroll
            for (int c = 0; c < 4; ++c) {
                u64 k = (c == 0) ? kw0 : (c == 1) ? kw1 : (c == 2) ? kw2 : kw3;
                while (k) {
                    int bpos = (int)__builtin_ctzll(k); k &= k - 1;
                    if ((idx & 7) == wid) {
                        int row = ((W + c) << 6) + bpos;
                        int sl = nmine & 3;
                        if (sl == 0) b0 = row;
                        else if (sl == 1) b1 = row;
                        else if (sl == 2) b2 = row;
                        else b3 = row;
                        nmine++;
                        if ((nmine & 3) == 0 && lactive) {
                            ulonglong2 m0 = *(const ulonglong2*)(bp + (size_t)b0 * NWORDS);
                            ulonglong2 m1 = *(const ulonglong2*)(bp + (size_t)b1 * NWORDS);
                            ulonglong2 m2 = *(const ulonglong2*)(bp + (size_t)b2 * NWORDS);
                            ulonglong2 m3 = *(const ulonglong2*)(bp + (size_t)b3 * NWORDS);
                            scrow[Wp4 + 2 * lane]     |= m0.x | m1.x | m2.x | m3.x;
                            scrow[Wp4 + 2 * lane + 1] |= m0.y | m1.y | m2.y | m3.y;
                        }
                    }
                    idx++;
                }
            }
            if ((nmine & 3) != 0 && lactive) {
                int n = nmine & 3;
                int a1 = (n > 1) ? b1 : b0, a2 = (n > 2) ? b2 : b0;
                ulonglong2 m0 = *(const ulonglong2*)(bp + (size_t)b0 * NWORDS);
                ulonglong2 m1 = *(const ulonglong2*)(bp + (size_t)a1 * NWORDS);
                ulonglong2 m2 = *(const ulonglong2*)(bp + (size_t)a2 * NWORDS);
                scrow[Wp4 + 2 * lane]     |= m0.x | m1.x | m2.x;
                scrow[Wp4 + 2 * lane + 1] |= m0.y | m1.y | m2.y;
            }
        }
        __syncthreads();   // B: SUPC + SLICE[buf^1] ready for next group
    }

    // b_nms loss over kept boxes (all 512 threads)
    float nl = 0.0f, nc = 0.0f;
    for (int p = tid; p < M_BOXES; p += 512) {
        if ((KW[p >> 6] >> (p & 63)) & 1ull) {
            nl += box_loss_term(sc5[p], sconf[p]);
            nc += 1.0f;
        }
    }
    nl = wave_sum(nl);
    nc = wave_sum(nc);
    if (lane == 0) { fred[wid] = nl; fred[8 + wid] = nc; }
    __syncthreads();
    if (tid == 0) {
        float tnl = 0.0f, tnc = 0.0f;
#pragma unroll
        for (int k = 0; k < 8; ++k) { tnl += fred[k]; tnc += fred[8 + k]; }
        float p_loss = acc[0], r_loss = acc[1], b_loss = acc[2], b_cnt = acc[3];
        float yolo = b_loss + tnl * (b_cnt / fmaxf(tnc, 1.0f));
        out[0] = r_loss * 0.8f + yolo + p_loss;
    }
}

// ---------------------------------------------------------------------------
extern "C" void kernel_launch(void* const* d_in, const int* in_sizes, int n_in,
                              void* d_out, int out_size, void* d_ws, size_t ws_size,
                              hipStream_t stream) {
    const float* img   = (const float*)d_in[0];
    const float* p0    = (const float*)d_in[1];
    const float* p1    = (const float*)d_in[2];
    const float* p2    = (const float*)d_in[3];
    const float* probs = (const float*)d_in[4];
    const float* boxes = (const float*)d_in[5];
    float* out = (float*)d_out;

    char* ws = (char*)d_ws;
    float* acc = (float*)ws;                // acc[0..3]
    int* nvp = (int*)(ws + 32);             // nvalid
    float* sx1 = (float*)(ws + 1024);
    float* sy1 = sx1 + M_BOXES;
    float* sx2 = sy1 + M_BOXES;
    float* sy2 = sx2 + M_BOXES;
    float* sarea = sy2 + M_BOXES;
    float* sconf = sarea + M_BOXES;
    float* sc5 = sconf + M_BOXES;
    // mask: 6144 rows x 96 words x 8 B = 4.72 MB @ offset 173056 (16-aligned)
    u64* mask = (u64*)(ws + 173056);

    hipMemsetAsync(acc, 0, 64, stream);
    sort_boxes<<<1, 1024, 0, stream>>>(boxes, sx1, sy1, sx2, sy2, sarea, sconf, sc5, nvp);
    mega_kernel<<<MB_BLOCKS + P_BLOCKS + R_BLOCKS + B_BLOCKS, 256, 0, stream>>>(
        img, p0, p1, p2, probs, boxes, sx1, sy1, sx2, sy2, sarea, nvp, mask, acc);
    nms_walk<<<1, 512, 0, stream>>>(acc, nvp, mask, sconf, sc5, out);
}